// Round 3
// baseline (14804.062 us; speedup 1.0000x reference)
//
#include <hip/hip_runtime.h>
#include <math.h>

#define T_ 100
#define B_ 64
#define S_ 128
#define E_ 512
#define H_ 1024
#define C_ 512
#define V_ 32000
#define TS_ 99            // T-1 steps
#define R_ (TS_ * B_)     // 6336 rows
#define MP_ 6400          // rows padded to multiple of 128 for MFMA
#define NT2 250           // vocab n-tiles of 128
#define NBLK 64           // persistent-kernel grid size

typedef unsigned short ushort_t;
typedef __attribute__((ext_vector_type(8))) short short8;
typedef __attribute__((ext_vector_type(4))) float f32x4;

__device__ __forceinline__ float sigm_(float x) { return 1.0f / (1.0f + __expf(-x)); }
__device__ __forceinline__ float tanh_(float x) { float e = __expf(2.0f * x); return 1.0f - 2.0f / (e + 1.0f); }
__device__ __forceinline__ ushort_t f2bf(float f) {
    unsigned u = __float_as_uint(f);
    unsigned r = (u + 0x7FFF + ((u >> 16) & 1)) >> 16;
    return (ushort_t)r;
}
__device__ __forceinline__ float bf2f(ushort_t u) { return __uint_as_float(((unsigned)u) << 16); }

__device__ __forceinline__ float wred(float v) {
    #pragma unroll
    for (int o = 32; o; o >>= 1) v += __shfl_down(v, o);
    return v;
}
__device__ __forceinline__ float wmax(float v) {
    #pragma unroll
    for (int o = 32; o; o >>= 1) v = fmaxf(v, __shfl_down(v, o));
    return v;
}

// Device-scope grid barrier, monotonic generation (no counter reset race).
__device__ __forceinline__ void gbar(int* cnt, int* gen, int k) {
    __syncthreads();
    if (threadIdx.x == 0) {
        __threadfence();
        int v = __hip_atomic_fetch_add(cnt, 1, __ATOMIC_ACQ_REL, __HIP_MEMORY_SCOPE_AGENT);
        if (v == k * NBLK + (NBLK - 1)) {
            __hip_atomic_store(gen, k + 1, __ATOMIC_RELEASE, __HIP_MEMORY_SCOPE_AGENT);
        } else {
            while (__hip_atomic_load(gen, __ATOMIC_RELAXED, __HIP_MEMORY_SCOPE_AGENT) < k + 1) {
                __builtin_amdgcn_s_sleep(1);
            }
        }
        __threadfence();
    }
    __syncthreads();
}

// ---------------------------------------------------------------------------
// Fused GRU phase (runs inside persistent kernel). 64 blocks, block owns 16 j.
// Wp packed [3072][1536] bf16: row c=3*jj+g = [Wih[g*1024+jj][0:512] | Whh[g*1024+jj][0:1024]].
// x-part and h-part accumulated separately (n-gate needs r*h_n).
// ---------------------------------------------------------------------------
__device__ __forceinline__ void gru_phase(
    int tid, int c0,
    const ushort_t* __restrict__ ax,   // [64][512] bf16
    const ushort_t* __restrict__ ah,   // [64][1024] bf16
    const ushort_t* __restrict__ Wp,   // packed weights
    const float* __restrict__ bi, const float* __restrict__ bh,
    const float* __restrict__ hprevf,  // [64][1024] fp32
    float* __restrict__ houtf,         // [64][1024] fp32
    ushort_t* __restrict__ houtbf,     // [64][1024] bf16
    float (*pl)[12][256])
{
    const int w = tid >> 6, lane = tid & 63, quad = lane >> 4, l16 = lane & 15;
    f32x4 accX[12] = {};
    f32x4 accH[12] = {};
    const int kc0 = w * 12;   // 48 kc total: kc<16 -> x (K=512), kc>=16 -> h (K=1024)
    #pragma unroll
    for (int i = 0; i < 12; ++i) {
        const int kc = kc0 + i;
        const int kw = kc * 32 + quad * 8;
        short8 bfr[3];
        #pragma unroll
        for (int ct = 0; ct < 3; ++ct)
            bfr[ct] = *(const short8*)(Wp + (size_t)(c0 + ct * 16 + l16) * 1536 + kw);
        short8 af[4];
        if (kc < 16) {
            #pragma unroll
            for (int mt = 0; mt < 4; ++mt)
                af[mt] = *(const short8*)(ax + (size_t)(mt * 16 + l16) * 512 + kw);
            #pragma unroll
            for (int mt = 0; mt < 4; ++mt)
                #pragma unroll
                for (int ct = 0; ct < 3; ++ct)
                    accX[mt * 3 + ct] = __builtin_amdgcn_mfma_f32_16x16x32_bf16(af[mt], bfr[ct], accX[mt * 3 + ct], 0, 0, 0);
        } else {
            const int ko = (kc - 16) * 32 + quad * 8;
            #pragma unroll
            for (int mt = 0; mt < 4; ++mt)
                af[mt] = *(const short8*)(ah + (size_t)(mt * 16 + l16) * 1024 + ko);
            #pragma unroll
            for (int mt = 0; mt < 4; ++mt)
                #pragma unroll
                for (int ct = 0; ct < 3; ++ct)
                    accH[mt * 3 + ct] = __builtin_amdgcn_mfma_f32_16x16x32_bf16(af[mt], bfr[ct], accH[mt * 3 + ct], 0, 0, 0);
        }
    }
    // two-round LDS reduce (X then H) into 48 KB plane buffer
    #pragma unroll
    for (int t = 0; t < 12; ++t)
        #pragma unroll
        for (int r = 0; r < 4; ++r)
            pl[w][t][(quad * 4 + r) * 16 + l16] = accX[t][r];
    __syncthreads();
    float X[4][3], H[4][3];
    #pragma unroll
    for (int q = 0; q < 4; ++q) {
        int o = tid + q * 256, b = o >> 4, jl = o & 15;
        int mt = b >> 4, idx = (b & 15) * 16;
        #pragma unroll
        for (int g = 0; g < 3; ++g) {
            int c = jl * 3 + g;
            int p = mt * 3 + (c >> 4), e = idx + (c & 15);
            X[q][g] = pl[0][p][e] + pl[1][p][e] + pl[2][p][e] + pl[3][p][e];
        }
    }
    __syncthreads();
    #pragma unroll
    for (int t = 0; t < 12; ++t)
        #pragma unroll
        for (int r = 0; r < 4; ++r)
            pl[w][t][(quad * 4 + r) * 16 + l16] = accH[t][r];
    __syncthreads();
    #pragma unroll
    for (int q = 0; q < 4; ++q) {
        int o = tid + q * 256, b = o >> 4, jl = o & 15;
        int mt = b >> 4, idx = (b & 15) * 16;
        #pragma unroll
        for (int g = 0; g < 3; ++g) {
            int c = jl * 3 + g;
            int p = mt * 3 + (c >> 4), e = idx + (c & 15);
            H[q][g] = pl[0][p][e] + pl[1][p][e] + pl[2][p][e] + pl[3][p][e];
        }
    }
    const int j0 = c0 / 3;
    #pragma unroll
    for (int q = 0; q < 4; ++q) {
        int o = tid + q * 256, b = o >> 4, jl = o & 15;
        int j = j0 + jl;
        float r = sigm_(X[q][0] + H[q][0] + bi[j] + bh[j]);
        float z = sigm_(X[q][1] + H[q][1] + bi[1024 + j] + bh[1024 + j]);
        float n = tanh_(X[q][2] + bi[2048 + j] + r * (H[q][2] + bh[2048 + j]));
        float hp = hprevf[b * 1024 + j];
        float h = (1.0f - z) * n + z * hp;
        houtf[b * 1024 + j] = h;
        houtbf[b * 1024 + j] = f2bf(h);
    }
}

// ---------------------------------------------------------------------------
// Persistent decode loop: 64 blocks x 256 threads, 4 phases + 4 barriers/step.
// ---------------------------------------------------------------------------
__global__ __launch_bounds__(256, 1) void decode_persist(
    const ushort_t* __restrict__ xembbf,   // [R_][512]
    const ushort_t* __restrict__ ctxpbf,   // [S*B][512]
    const ushort_t* __restrict__ ctxbf,    // [S*B][512]
    const ushort_t* __restrict__ Wp0,
    const ushort_t* __restrict__ Wp1,
    const ushort_t* __restrict__ Wh2cbf,   // [512][1024]
    const float* __restrict__ bi0, const float* __restrict__ bh0,
    const float* __restrict__ bi1, const float* __restrict__ bh1,
    const float* __restrict__ wmlp,
    const float* __restrict__ zerof,       // 64*1024 zeros (bf16 view also zero)
    float* __restrict__ h1f, ushort_t* __restrict__ h1bf,
    float* __restrict__ h2f, ushort_t* __restrict__ h2bfall,
    float* __restrict__ hid, ushort_t* __restrict__ zbf,
    int* cnt, int* gen)
{
    __shared__ float pl[4][12][256];   // 48 KB
    __shared__ float aux[1184];        // hd 512 | wm 512 | sc 128
    const int bid = blockIdx.x, tid = threadIdx.x;
    const int w = tid >> 6, lane = tid & 63, quad = lane >> 4, l16 = lane & 15;
    const ushort_t* zerobf = (const ushort_t*)zerof;
    int bk = 0;
    for (int t = 0; t < TS_; ++t) {
        const ushort_t* hprevbf = t ? (h2bfall + (size_t)(t - 1) * 65536) : zerobf;
        const float* hprevf = t ? h2f : zerof;
        // ---- P1: GRU0 -> h1 ----
        gru_phase(tid, bid * 48, xembbf + (size_t)t * 32768, hprevbf, Wp0,
                  bi0, bh0, hprevf, h1f, h1bf, pl);
        gbar(cnt, gen, bk++);
        // ---- P2: hid = h1 @ W_h2c^T (32 blocks) ----
        if (bid < 32) {
            const int c0 = bid * 16;
            f32x4 acc[4] = {};
            #pragma unroll
            for (int i = 0; i < 8; ++i) {
                const int kc = w * 8 + i;
                const int ko = kc * 32 + quad * 8;
                short8 bfr = *(const short8*)(Wh2cbf + (size_t)(c0 + l16) * 1024 + ko);
                #pragma unroll
                for (int mt = 0; mt < 4; ++mt) {
                    short8 af = *(const short8*)(h1bf + (size_t)(mt * 16 + l16) * 1024 + ko);
                    acc[mt] = __builtin_amdgcn_mfma_f32_16x16x32_bf16(af, bfr, acc[mt], 0, 0, 0);
                }
            }
            #pragma unroll
            for (int mt = 0; mt < 4; ++mt)
                #pragma unroll
                for (int r = 0; r < 4; ++r)
                    pl[w][mt][(quad * 4 + r) * 16 + l16] = acc[mt][r];
            __syncthreads();
            const int mr = tid >> 4, cc = tid & 15;
            #pragma unroll
            for (int mt = 0; mt < 4; ++mt)
                hid[(size_t)(mt * 16 + mr) * 512 + c0 + cc] =
                    pl[0][mt][tid] + pl[1][mt][tid] + pl[2][mt][tid] + pl[3][mt][tid];
        }
        gbar(cnt, gen, bk++);
        // ---- P3: attention -> zbf (64 blocks, one per b) ----
        {
            const int b = bid;
            float* hd = aux;
            float* wm = aux + 512;
            float* sc = aux + 1024;
            for (int k2 = tid; k2 < 512; k2 += 256) { hd[k2] = hid[b * 512 + k2]; wm[k2] = wmlp[k2]; }
            __syncthreads();
            for (int s = w * 32; s < w * 32 + 32; ++s) {
                const short8 v8 = *(const short8*)(ctxpbf + ((size_t)s * 64 + b) * 512 + lane * 8);
                float acc = 0;
                #pragma unroll
                for (int e = 0; e < 8; ++e) {
                    int c = lane * 8 + e;
                    acc += tanh_(bf2f((ushort_t)v8[e]) + hd[c]) * wm[c];
                }
                acc = wred(acc);
                if (lane == 0) sc[s] = acc;
            }
            __syncthreads();
            if (w == 0) {
                float s0 = sc[lane], s1 = sc[lane + 64];
                float m = fmaxf(s0, s1);
                m = wmax(m); m = __shfl(m, 0);
                float e0 = __expf(s0 - m), e1 = __expf(s1 - m);
                float ssum = wred(e0 + e1); ssum = __shfl(ssum, 0);
                float inv = 1.0f / ssum;
                sc[lane] = e0 * inv; sc[lane + 64] = e1 * inv;
            }
            __syncthreads();
            {
                const int c2 = tid * 2;
                float a0 = 0, a1 = 0;
                #pragma unroll 8
                for (int s = 0; s < 128; ++s) {
                    float al = sc[s];
                    ushort2 u = *(const ushort2*)(ctxbf + ((size_t)s * 64 + b) * 512 + c2);
                    a0 += al * bf2f(u.x);
                    a1 += al * bf2f(u.y);
                }
                zbf[b * 512 + c2] = f2bf(a0);
                zbf[b * 512 + c2 + 1] = f2bf(a1);
            }
        }
        gbar(cnt, gen, bk++);
        // ---- P4: GRU1 -> h2 ----
        gru_phase(tid, bid * 48, zbf, h1bf, Wp1,
                  bi1, bh1, h1f, h2f, h2bfall + (size_t)t * 65536, pl);
        gbar(cnt, gen, bk++);
    }
}

// ---------------------------------------------------------------------------
// fp32-in bf16-out tiled GEMM-NT for ctx_p precompute.
// ---------------------------------------------------------------------------
__global__ __launch_bounds__(256) void gemm_nt_bf(const float* __restrict__ A,
                                                  const float* __restrict__ Bw,
                                                  ushort_t* __restrict__ Cbf,
                                                  int N, int K) {
    __shared__ __align__(16) float As[16][68];
    __shared__ __align__(16) float Bs[16][68];
    const int tid = threadIdx.x;
    const int m0 = blockIdx.y * 64, n0 = blockIdx.x * 64;
    const int tx = tid & 15, ty = tid >> 4;
    const int lr = tid >> 2, lk = (tid & 3) << 2;
    float acc[4][4] = {};
    const float* Ap = A + (size_t)(m0 + lr) * K + lk;
    const float* Bp = Bw + (size_t)(n0 + lr) * K + lk;
    for (int kt = 0; kt < K; kt += 16) {
        float4 av = *(const float4*)(Ap + kt);
        float4 bv = *(const float4*)(Bp + kt);
        __syncthreads();
        As[lk + 0][lr] = av.x; As[lk + 1][lr] = av.y; As[lk + 2][lr] = av.z; As[lk + 3][lr] = av.w;
        Bs[lk + 0][lr] = bv.x; Bs[lk + 1][lr] = bv.y; Bs[lk + 2][lr] = bv.z; Bs[lk + 3][lr] = bv.w;
        __syncthreads();
        #pragma unroll
        for (int kk = 0; kk < 16; ++kk) {
            float4 a = *(const float4*)&As[kk][ty << 2];
            float4 b = *(const float4*)&Bs[kk][tx << 2];
            float ar[4] = {a.x, a.y, a.z, a.w};
            float br[4] = {b.x, b.y, b.z, b.w};
            #pragma unroll
            for (int i = 0; i < 4; ++i)
                #pragma unroll
                for (int j = 0; j < 4; ++j) acc[i][j] = fmaf(ar[i], br[j], acc[i][j]);
        }
    }
    #pragma unroll
    for (int i = 0; i < 4; ++i)
        #pragma unroll
        for (int j = 0; j < 4; ++j)
            Cbf[(size_t)(m0 + (ty << 2) + i) * N + n0 + (tx << 2) + j] = f2bf(acc[i][j]);
}

// ---------------------------------------------------------------------------
// bf16 MFMA GEMM-NT, 128x128 tile (tail). EPI==1: tanh(acc+bias) -> bf16 C.
// EPI==2: fused per-row online-LSE partials -> pp[row][ntile]=(max,sum).
// ---------------------------------------------------------------------------
template <int EPI>
__global__ __launch_bounds__(256) void mfma_nt(const ushort_t* __restrict__ A,
                                               const ushort_t* __restrict__ Bw,
                                               const float* __restrict__ bias,
                                               ushort_t* __restrict__ Cbf,
                                               float2* __restrict__ pp,
                                               int N, int K, int NT) {
    __shared__ ushort_t As[128 * 72];
    __shared__ ushort_t Bs[128 * 72];
    __shared__ float smM[2][128], smS[2][128];
    const int tid = threadIdx.x;
    const int m0 = blockIdx.y * 128, n0 = blockIdx.x * 128;
    const int w = tid >> 6, lane = tid & 63;
    const int quad = lane >> 4, l16 = lane & 15;
    f32x4 acc[4][4] = {};
    for (int kc = 0; kc < K; kc += 64) {
        __syncthreads();
        #pragma unroll
        for (int i = 0; i < 4; ++i) {
            int cid = i * 256 + tid;
            int row = cid >> 3, c8 = cid & 7;
            uint4 va = *(const uint4*)(A + (size_t)(m0 + row) * K + kc + c8 * 8);
            *(uint4*)(&As[row * 72 + c8 * 8]) = va;
            uint4 vb = *(const uint4*)(Bw + (size_t)(n0 + row) * K + kc + c8 * 8);
            *(uint4*)(&Bs[row * 72 + c8 * 8]) = vb;
        }
        __syncthreads();
        #pragma unroll
        for (int ks = 0; ks < 2; ++ks) {
            short8 af[4], bfr[4];
            #pragma unroll
            for (int i = 0; i < 4; ++i)
                af[i] = *(const short8*)(&As[((w >> 1) * 64 + i * 16 + l16) * 72 + ks * 32 + quad * 8]);
            #pragma unroll
            for (int j = 0; j < 4; ++j)
                bfr[j] = *(const short8*)(&Bs[((w & 1) * 64 + j * 16 + l16) * 72 + ks * 32 + quad * 8]);
            #pragma unroll
            for (int i = 0; i < 4; ++i)
                #pragma unroll
                for (int j = 0; j < 4; ++j)
                    acc[i][j] = __builtin_amdgcn_mfma_f32_16x16x32_bf16(af[i], bfr[j], acc[i][j], 0, 0, 0);
        }
    }
    const int colbase = n0 + (w & 1) * 64;
    const int rowbase = m0 + (w >> 1) * 64;
    if (EPI == 1) {
        #pragma unroll
        for (int j = 0; j < 4; ++j) {
            int col = colbase + j * 16 + l16;
            float bv = bias[col];
            #pragma unroll
            for (int i = 0; i < 4; ++i)
                #pragma unroll
                for (int r = 0; r < 4; ++r) {
                    int row = rowbase + i * 16 + quad * 4 + r;
                    Cbf[(size_t)row * N + col] = f2bf(tanh_(acc[i][j][r] + bv));
                }
        }
    } else {
        float bv[4];
        #pragma unroll
        for (int j = 0; j < 4; ++j) bv[j] = bias[colbase + j * 16 + l16];
        #pragma unroll
        for (int i = 0; i < 4; ++i) {
            #pragma unroll
            for (int r = 0; r < 4; ++r) {
                float x0 = acc[i][0][r] + bv[0], x1 = acc[i][1][r] + bv[1];
                float x2 = acc[i][2][r] + bv[2], x3 = acc[i][3][r] + bv[3];
                float mx = fmaxf(fmaxf(x0, x1), fmaxf(x2, x3));
                #pragma unroll
                for (int o = 1; o < 16; o <<= 1) mx = fmaxf(mx, __shfl_xor(mx, o));
                float s = __expf(x0 - mx) + __expf(x1 - mx) + __expf(x2 - mx) + __expf(x3 - mx);
                #pragma unroll
                for (int o = 1; o < 16; o <<= 1) s += __shfl_xor(s, o);
                if (l16 == 0) {
                    int rr = (w >> 1) * 64 + i * 16 + quad * 4 + r;
                    smM[w & 1][rr] = mx;
                    smS[w & 1][rr] = s;
                }
            }
        }
        __syncthreads();
        if (tid < 128) {
            float ma = smM[0][tid], mb = smM[1][tid];
            float M = fmaxf(ma, mb);
            float S = smS[0][tid] * __expf(ma - M) + smS[1][tid] * __expf(mb - M);
            pp[(size_t)(m0 + tid) * NT + blockIdx.x] = make_float2(M, S);
        }
    }
}

// fp32 -> bf16 convert. block 256, 4 elems/thread.
__global__ __launch_bounds__(256) void conv_bf16(const float* __restrict__ src,
                                                 ushort_t* __restrict__ dst,
                                                 long long n) {
    long long base = ((long long)blockIdx.x * 256 + threadIdx.x) * 4;
    if (base >= n) return;
    float4 v = *(const float4*)(src + base);
    *(ushort2*)(dst + base) = make_ushort2(f2bf(v.x), f2bf(v.y));
    *(ushort2*)(dst + base + 2) = make_ushort2(f2bf(v.z), f2bf(v.w));
}

// pack GRU weights: row c = 3*jj+g -> [Wih[g*1024+jj][0:512] | Whh[g*1024+jj][0:1024]], bf16.
__global__ __launch_bounds__(256) void pack_gru(const float* __restrict__ Wih,
                                                const float* __restrict__ Whh,
                                                ushort_t* __restrict__ Wp) {
    const int c = blockIdx.x;           // 0..3071
    const int jj = c / 3, g = c % 3;
    const int src = g * 1024 + jj;
    ushort_t* dst = Wp + (size_t)c * 1536;
    for (int k = threadIdx.x; k < 512; k += 256) dst[k] = f2bf(Wih[(size_t)src * 512 + k]);
    for (int k = threadIdx.x; k < 1024; k += 256) dst[512 + k] = f2bf(Whh[(size_t)src * 1024 + k]);
}

// gather embedding rows -> bf16: xall[r] = bf16(emb[y[r]])
__global__ __launch_bounds__(128) void gather_emb_bf(const float* __restrict__ emb,
                                                     const int* __restrict__ y,
                                                     ushort_t* __restrict__ xall) {
    const int r = blockIdx.x;
    const int tok = y[r];
    const float* src = emb + (size_t)tok * 512;
    ushort_t* dst = xall + (size_t)r * 512;
    int k = threadIdx.x * 4;
    float4 v = *(const float4*)(src + k);
    *(ushort2*)(dst + k) = make_ushort2(f2bf(v.x), f2bf(v.y));
    *(ushort2*)(dst + k + 2) = make_ushort2(f2bf(v.z), f2bf(v.w));
}

// combine LSE partials + target logit -> per-row loss. grid = R_, block 64.
__global__ __launch_bounds__(64) void row_loss_k(const float2* __restrict__ pp,
                                                 const ushort_t* __restrict__ lg,
                                                 const ushort_t* __restrict__ Wvbf,
                                                 const float* __restrict__ bv,
                                                 const int* __restrict__ y,
                                                 float* __restrict__ rl) {
    const int r = blockIdx.x;
    const int lane = threadIdx.x;
    const int t = r / B_, b = r % B_;
    const int tgt = y[(t + 1) * B_ + b];
    float m = -1e30f;
    for (int i = lane; i < NT2; i += 64) m = fmaxf(m, pp[(size_t)r * NT2 + i].x);
    m = wmax(m); m = __shfl(m, 0);
    float s = 0;
    for (int i = lane; i < NT2; i += 64) {
        float2 p = pp[(size_t)r * NT2 + i];
        s += p.y * __expf(p.x - m);
    }
    s = wred(s);
    float d = 0;
    for (int k = lane; k < E_; k += 64)
        d += bf2f(lg[(size_t)r * E_ + k]) * bf2f(Wvbf[(size_t)tgt * E_ + k]);
    d = wred(d);
    if (lane == 0) {
        float lse = m + logf(s);
        rl[r] = (tgt != 0) ? (lse - (d + bv[tgt])) : 0.0f;
    }
}

__global__ __launch_bounds__(256) void sum_k(const float* __restrict__ rl, float* __restrict__ out) {
    float s = 0;
    for (int i = threadIdx.x; i < R_; i += 256) s += rl[i];
    __shared__ float red[4];
    s = wred(s);
    if ((threadIdx.x & 63) == 0) red[threadIdx.x >> 6] = s;
    __syncthreads();
    if (threadIdx.x == 0) out[0] = red[0] + red[1] + red[2] + red[3];
}

extern "C" void kernel_launch(void* const* d_in, const int* in_sizes, int n_in,
                              void* d_out, int out_size, void* d_ws, size_t ws_size,
                              hipStream_t stream) {
    const int*   y     = (const int*)d_in[0];
    const float* ctx   = (const float*)d_in[1];
    const float* emb   = (const float*)d_in[2];
    const float* W_ih0 = (const float*)d_in[3];
    const float* W_hh0 = (const float*)d_in[4];
    const float* b_ih0 = (const float*)d_in[5];
    const float* b_hh0 = (const float*)d_in[6];
    const float* W_ih1 = (const float*)d_in[7];
    const float* W_hh1 = (const float*)d_in[8];
    const float* b_ih1 = (const float*)d_in[9];
    const float* b_hh1 = (const float*)d_in[10];
    const float* W_c2c = (const float*)d_in[11];
    const float* W_h2c = (const float*)d_in[12];
    const float* w_mlp = (const float*)d_in[13];
    const float* W_h2o = (const float*)d_in[14];
    const float* b_h2o = (const float*)d_in[15];
    const float* W_o2p = (const float*)d_in[16];
    const float* b_o2p = (const float*)d_in[17];
    float* out = (float*)d_out;

    char* base = (char*)d_ws;
    auto alloc = [&](size_t bytes) { char* p = base; base += (bytes + 255) & ~(size_t)255; return p; };
    int* bar          = (int*)alloc(256);
    ushort_t* ctxpbf  = (ushort_t*)alloc((size_t)S_ * B_ * C_ * 2);   // 8.39 MB
    ushort_t* ctxbf   = (ushort_t*)alloc((size_t)S_ * B_ * C_ * 2);   // 8.39 MB
    ushort_t* xembbf  = (ushort_t*)alloc((size_t)R_ * E_ * 2);        // 6.49 MB (pp overlays)
    ushort_t* Wp0     = (ushort_t*)alloc((size_t)3072 * 1536 * 2);    // 9.44 MB
    ushort_t* Wp1     = (ushort_t*)alloc((size_t)3072 * 1536 * 2);    // 9.44 MB (lg_bf overlays)
    ushort_t* Wh2cbf  = (ushort_t*)alloc((size_t)C_ * H_ * 2);
    ushort_t* Wh2obf  = (ushort_t*)alloc((size_t)E_ * H_ * 2);
    ushort_t* Wo2pbf  = (ushort_t*)alloc((size_t)V_ * E_ * 2);        // 32.8 MB
    ushort_t* h2bfall = (ushort_t*)alloc((size_t)MP_ * H_ * 2);       // 13.1 MB
    float* h1f        = (float*)alloc((size_t)B_ * H_ * 4);
    ushort_t* h1bf    = (ushort_t*)alloc((size_t)B_ * H_ * 2);
    float* h2f        = (float*)alloc((size_t)B_ * H_ * 4);
    float* zerof      = (float*)alloc((size_t)B_ * H_ * 4);
    float* hid        = (float*)alloc((size_t)B_ * C_ * 4);
    ushort_t* zbf     = (ushort_t*)alloc((size_t)B_ * C_ * 2);
    float* rl         = (float*)alloc((size_t)R_ * 4);
    // overlays (loop-only regions reused by tail-only buffers):
    float2* pp        = (float2*)xembbf;    // 12.8 MB <= xembbf+Wp0 (15.9 MB)
    ushort_t* lg_bf   = Wp1;                // 6.55 MB <= Wp1 (9.44 MB)

    // ---- init (zeroed every launch; ws is re-poisoned by harness) ----
    hipMemsetAsync(bar, 0, 256, stream);
    hipMemsetAsync(zerof, 0, (size_t)B_ * H_ * 4, stream);
    hipMemsetAsync(h2bfall + (size_t)R_ * H_, 0, (size_t)(MP_ - R_) * H_ * 2, stream);

    // ---- precompute (bf16 conversions, packing, ctx_p) ----
    gemm_nt_bf<<<dim3(C_ / 64, (S_ * B_) / 64), 256, 0, stream>>>(ctx, W_c2c, ctxpbf, C_, C_);
    conv_bf16<<<((size_t)S_ * B_ * C_ / 4 + 255) / 256, 256, 0, stream>>>(ctx, ctxbf, (long long)S_ * B_ * C_);
    gather_emb_bf<<<R_, 128, 0, stream>>>(emb, y, xembbf);
    pack_gru<<<3072, 256, 0, stream>>>(W_ih0, W_hh0, Wp0);
    pack_gru<<<3072, 256, 0, stream>>>(W_ih1, W_hh1, Wp1);
    conv_bf16<<<((size_t)C_ * H_ / 4 + 255) / 256, 256, 0, stream>>>(W_h2c, Wh2cbf, (long long)C_ * H_);
    conv_bf16<<<((size_t)E_ * H_ / 4 + 255) / 256, 256, 0, stream>>>(W_h2o, Wh2obf, (long long)E_ * H_);
    conv_bf16<<<((size_t)V_ * E_ / 4 + 255) / 256, 256, 0, stream>>>(W_o2p, Wo2pbf, (long long)V_ * E_);

    // ---- persistent sequential decode loop ----
    decode_persist<<<NBLK, 256, 0, stream>>>(xembbf, ctxpbf, ctxbf, Wp0, Wp1, Wh2cbf,
                                             b_ih0, b_hh0, b_ih1, b_hh1, w_mlp, zerof,
                                             h1f, h1bf, h2f, h2bfall, hid, zbf,
                                             bar, bar + 1);

    // ---- batched tail (bf16 MFMA) ----
    mfma_nt<1><<<dim3(E_ / 128, MP_ / 128), 256, 0, stream>>>(h2bfall, Wh2obf, b_h2o,
                                                              lg_bf, nullptr, E_, H_, 0);
    mfma_nt<2><<<dim3(V_ / 128, MP_ / 128), 256, 0, stream>>>(lg_bf, Wo2pbf, b_o2p,
                                                              nullptr, pp, V_, E_, NT2);
    row_loss_k<<<R_, 64, 0, stream>>>(pp, lg_bf, Wo2pbf, b_o2p, y, rl);
    sum_k<<<1, 256, 0, stream>>>(rl, out);
}